// Round 1
// baseline (168.326 us; speedup 1.0000x reference)
//
#include <hip/hip_runtime.h>

// PositionEncoding: out[b,s,:] = is_class ? E_class[class_ids[b,s],:]
//                                         : interleaved sin/cos(v * 2^i * pi)
// B=64, S=8192, CLASS_NUM=4096, LEVELS=32, E=64. Output fp32, 134 MB -> memory-bound.
//
// Numerics: reference computes sin(fp32(v * 2^i * pi_f)). Power-of-2 scaling is
// exact in fp32, so the reference argument == 2^i * w with w = fp32(v * pi_f).
// We track revolutions in double: u0 = w/(2pi); u_L = u0 * 2^L (exact);
// frac(u_L) feeds hardware v_sin_f32/v_cos_f32 (revolution input). Total error
// ~2e-7 revolutions vs threshold 8.9e-2 absolute.

constexpr int ROWS   = 64 * 8192;       // B*S
constexpr int CHUNKS = ROWS * 16;       // one float4 (2 levels) per chunk

__global__ __launch_bounds__(256) void PositionEncoding_61856118997301_kernel(
    const float* __restrict__ values,
    const float* __restrict__ E_class,
    const int*   __restrict__ class_ids,
    const int*   __restrict__ is_class,
    float4*      __restrict__ out)
{
    const float  PI_F    = 3.14159274101257324f;   // fp32(pi), matches reference freqs
    const double INV_2PI = 0.15915494309189535;    // double 1/(2*pi)

    int tid    = blockIdx.x * blockDim.x + threadIdx.x;
    int stride = gridDim.x * blockDim.x;

    for (int g = tid; g < CHUNKS; g += stride) {
        int row = g >> 4;        // which (b,s) element
        int j   = g & 15;        // which float4 of the 64-wide row -> levels 2j, 2j+1

        float4 r;
        if (is_class[row] != 0) {
            // 16 consecutive lanes read 16 consecutive float4s of one E_class row
            r = reinterpret_cast<const float4*>(E_class)[(class_ids[row] << 4) + j];
        } else {
            float  w  = values[row] * PI_F;          // fp32 round, == ref arg / 2^i
            double u0 = (double)w * INV_2PI;         // revolutions at level 0
            double uA = u0 * (double)(1 << (2 * j)); // level 2j   (exact scaling)
            double uB = uA + uA;                     // level 2j+1 (exact)
            // frac() exactly: uA < 2^29, uB < 2^30 -> int truncation is safe
            double fA = uA - (double)(int)uA;
            double fB = uB - (double)(int)uB;
            r.x = __builtin_amdgcn_sinf((float)fA);  // v_sin_f32: sin(2*pi*frac)
            r.y = __builtin_amdgcn_cosf((float)fA);
            r.z = __builtin_amdgcn_sinf((float)fB);
            r.w = __builtin_amdgcn_cosf((float)fB);
        }
        out[g] = r;   // wave store = 64 x 16B contiguous = 1 KB
    }
}

extern "C" void kernel_launch(void* const* d_in, const int* in_sizes, int n_in,
                              void* d_out, int out_size, void* d_ws, size_t ws_size,
                              hipStream_t stream) {
    const float* values    = (const float*)d_in[0];
    const float* E_class   = (const float*)d_in[1];
    const int*   class_ids = (const int*)d_in[2];
    const int*   is_class  = (const int*)d_in[3];
    float4*      out       = (float4*)d_out;

    dim3 block(256);
    dim3 grid(2048);   // grid-stride: 16 float4s per thread
    PositionEncoding_61856118997301_kernel<<<grid, block, 0, stream>>>(
        values, E_class, class_ids, is_class, out);
}